// Round 1
// baseline (20.417 us; speedup 1.0000x reference)
//
#include <hip/hip_runtime.h>

#define TIME_LEN 640
#define OUT_D 128
#define NUM_SB 512   // S*B = 8*64

__global__ __launch_bounds__(128) void sinenet_kernel(
    const float* __restrict__ x,    // [SB, T]
    const float* __restrict__ nlf,  // [SB]
    const float* __restrict__ tau,  // [SB]
    const float* __restrict__ a,    // [D]
    const float* __restrict__ phi,  // [D]
    float* __restrict__ out)        // [SB, D]
{
    constexpr float T_WAV      = 1.0f / 16000.0f;
    constexpr float LOG_F_STD  = 0.373288f;
    constexpr float LOG_F_MEAN = 5.02654f;
    constexpr double TWO_PI    = 6.283185307179586476925286766559;
    constexpr double INV_2PI   = 1.0 / TWO_PI;

    __shared__ float xs[TIME_LEN];

    const int sb = blockIdx.x;
    const int d  = threadIdx.x;

    // Stage x row into LDS (coalesced; 640 floats).
    const float* xrow = x + (size_t)sb * TIME_LEN;
    for (int t = d; t < TIME_LEN; t += 128) xs[t] = xrow[t];
    __syncthreads();

    const float fnlf = nlf[sb];
    const float ftau = tau[sb];
    // f computed exactly like the fp32 reference
    const float f = expf(fmaf(fnlf, LOG_F_STD, LOG_F_MEAN));

    const int   i  = d >> 2;            // harmonic index = d / NUM_CHANNELS
    const float fi = (float)i;
    const float ad   = a[d];
    const float phid = phi[d];

    // Phase in REVOLUTIONS: rev(t) = base_rev + t*step_rev.
    // base can be ~1e4 revs -> reduce mod 1 in double ONCE (loop-invariant).
    double base = ((double)phid - (double)fi * (double)f * (double)ftau) * INV_2PI;
    base -= floor(base);                 // [0,1)
    const float base_rev = (float)base;
    const float step_rev = (float)((double)fi * (double)f * (double)T_WAV * INV_2PI);

    float acc0 = 0.0f, acc1 = 0.0f;
    #pragma unroll 8
    for (int t = 0; t < TIME_LEN; t += 2) {
        float r0 = fmaf((float)t,       step_rev, base_rev);
        float r1 = fmaf((float)(t + 1), step_rev, base_rev);
        r0 = __builtin_amdgcn_fractf(r0);      // rev >= 0 always (base in [0,1))
        r1 = __builtin_amdgcn_fractf(r1);
        const float s0 = __builtin_amdgcn_sinf(r0);  // v_sin_f32: sin(2*pi*r)
        const float s1 = __builtin_amdgcn_sinf(r1);
        acc0 = fmaf(xs[t],     s0, acc0);
        acc1 = fmaf(xs[t + 1], s1, acc1);
    }

    out[(size_t)sb * OUT_D + d] = ad * (acc0 + acc1);
}

extern "C" void kernel_launch(void* const* d_in, const int* in_sizes, int n_in,
                              void* d_out, int out_size, void* d_ws, size_t ws_size,
                              hipStream_t stream) {
    const float* x   = (const float*)d_in[0];
    const float* nlf = (const float*)d_in[1];
    const float* tau = (const float*)d_in[2];
    const float* a   = (const float*)d_in[3];
    const float* phi = (const float*)d_in[4];
    float* out = (float*)d_out;

    sinenet_kernel<<<dim3(NUM_SB), dim3(128), 0, stream>>>(x, nlf, tau, a, phi, out);
}

// Round 2
// 9.957 us; speedup vs baseline: 2.0506x; 2.0506x over previous
//
#include <hip/hip_runtime.h>

#define TIME_LEN 640
#define OUT_D 128
#define NUM_SB 512   // S*B = 8*64

// h[sb,d] = a_d * sum_t x[sb,t] * sin(i_d*f_sb*(k_T[t]-tau_sb) + phi_d)
// Factorization: i_d = d>>2 has only 32 distinct values.
//   theta[t,i] = i*f*k_T[t]   (t,i only)
//   psi[d]     = phi_d - i*f*tau   (d only)
//   h_d = a_d * ( cos(psi_d)*P_i + sin(psi_d)*Q_i )
//   P_i = sum_t x_t sin(theta), Q_i = sum_t x_t cos(theta)
__global__ __launch_bounds__(512) void sinenet_kernel(
    const float* __restrict__ x,    // [SB, T]
    const float* __restrict__ nlf,  // [SB]
    const float* __restrict__ tau,  // [SB]
    const float* __restrict__ a,    // [D]
    const float* __restrict__ phi,  // [D]
    float* __restrict__ out)        // [SB, D]
{
    constexpr float T_WAV      = 1.0f / 16000.0f;
    constexpr float LOG_F_STD  = 0.373288f;
    constexpr float LOG_F_MEAN = 5.02654f;
    constexpr double INV_2PI_D = 0.15915494309189535;
    constexpr float  INV_2PI_F = 0.15915494309189535f;

    __shared__ float xs[TIME_LEN];
    __shared__ float PQ[2][32];

    const int sb  = blockIdx.x;
    const int tid = threadIdx.x;

    // stage x row (coalesced)
    const float* xrow = x + (size_t)sb * TIME_LEN;
    for (int t = tid; t < TIME_LEN; t += 512) xs[t] = xrow[t];

    const float f = expf(fmaf(nlf[sb], LOG_F_STD, LOG_F_MEAN));
    __syncthreads();

    // ---- Phase A: P_i, Q_i over the 640 x 32 (t,i) grid ----
    const int i = tid >> 4;     // 0..31 harmonic
    const int c = tid & 15;     // 0..15 t-chunk (lane-consecutive)

    // per-sample phase step in REVOLUTIONS (max ~0.15 rev)
    const float step_rev = (float)i * f * (T_WAV * INV_2PI_F);
    const float base     = step_rev * (float)c;     // phase at t=c
    const float step16   = step_rev * 16.0f;        // stride-16 step

    float P = 0.0f, Q = 0.0f;
    #pragma unroll 8
    for (int k = 0; k < TIME_LEN / 16; ++k) {       // 40 iters, t = c + 16k
        const float rev = fmaf((float)k, step16, base);   // <= ~93 revs
        const float rs  = __builtin_amdgcn_fractf(rev);          // sin arg
        const float rc  = __builtin_amdgcn_fractf(rs + 0.25f);   // cos arg
        const float sv  = __builtin_amdgcn_sinf(rs);  // v_sin: sin(2*pi*r)
        const float cv  = __builtin_amdgcn_sinf(rc);
        const float xv  = xs[c + (k << 4)];           // 4-lane broadcast, no conflict
        P = fmaf(xv, sv, P);
        Q = fmaf(xv, cv, Q);
    }
    // reduce the 16 c-partials (consecutive lanes within the wave)
    #pragma unroll
    for (int off = 1; off < 16; off <<= 1) {
        P += __shfl_xor(P, off);
        Q += __shfl_xor(Q, off);
    }
    if (c == 0) { PQ[0][i] = P; PQ[1][i] = Q; }
    __syncthreads();

    // ---- Phase B: epilogue over d ----
    if (tid < OUT_D) {
        const int d  = tid;
        const int id = d >> 2;
        // psi can be ~1e4 revs -> reduce mod 1 in double, once
        double psi = ((double)phi[d]
                    - (double)id * (double)f * (double)tau[sb]) * INV_2PI_D;
        psi -= floor(psi);                       // [0,1)
        const float pr = (float)psi;
        const float sp = __builtin_amdgcn_sinf(pr);
        const float cp = __builtin_amdgcn_sinf(__builtin_amdgcn_fractf(pr + 0.25f));
        out[(size_t)sb * OUT_D + d] = a[d] * fmaf(cp, PQ[0][id], sp * PQ[1][id]);
    }
}

extern "C" void kernel_launch(void* const* d_in, const int* in_sizes, int n_in,
                              void* d_out, int out_size, void* d_ws, size_t ws_size,
                              hipStream_t stream) {
    const float* x   = (const float*)d_in[0];
    const float* nlf = (const float*)d_in[1];
    const float* tau = (const float*)d_in[2];
    const float* a   = (const float*)d_in[3];
    const float* phi = (const float*)d_in[4];
    float* out = (float*)d_out;

    sinenet_kernel<<<dim3(NUM_SB), dim3(512), 0, stream>>>(x, nlf, tau, a, phi, out);
}

// Round 3
// 9.725 us; speedup vs baseline: 2.0995x; 1.0239x over previous
//
#include <hip/hip_runtime.h>

#define TIME_LEN 640
#define OUT_D 128
#define NUM_SB 512   // S*B = 8*64

// h[sb,d] = a_d * sum_t x[sb,t] * sin(i_d*f_sb*(k_T[t]-tau_sb) + phi_d),  i_d = d>>2 in 0..31
// Factorized:  h_d = a_d * ( cos(psi_d)*P_i + sin(psi_d)*Q_i ),
//   P_i = sum_t x_t sin(i*f*k_T[t]),  Q_i = sum_t x_t cos(i*f*k_T[t]),
//   psi_d = phi_d - i*f*tau  (reduced mod 2pi in double, once).
// Inner loop uses a rotation recurrence (4 FMA) instead of fract+v_sin.
__global__ __launch_bounds__(1024) void sinenet_kernel(
    const float* __restrict__ x,    // [SB, T]
    const float* __restrict__ nlf,  // [SB]
    const float* __restrict__ tau,  // [SB]
    const float* __restrict__ a,    // [D]
    const float* __restrict__ phi,  // [D]
    float* __restrict__ out)        // [SB, D]
{
    constexpr float T_WAV      = 1.0f / 16000.0f;
    constexpr float LOG_F_STD  = 0.373288f;
    constexpr float LOG_F_MEAN = 5.02654f;
    constexpr double INV_2PI_D = 0.15915494309189535;
    constexpr float  INV_2PI_F = 0.15915494309189535f;

    __shared__ float xs[TIME_LEN];
    __shared__ float PQ[2][32];

    const int sb  = blockIdx.x;
    const int tid = threadIdx.x;

    // stage x row (coalesced, one round)
    const float* xrow = x + (size_t)sb * TIME_LEN;
    if (tid < TIME_LEN) xs[tid] = xrow[tid];

    const float f = expf(fmaf(nlf[sb], LOG_F_STD, LOG_F_MEAN));

    const int i = tid >> 5;     // 0..31 harmonic
    const int c = tid & 31;     // 0..31 t-chunk (lane bits 0..4 -> shfl stays in half-wave)

    // ---- epilogue trig precomputed BEFORE the main loop (overlaps staging) ----
    float sp = 0.f, cp = 0.f, ad = 0.f;
    if (tid < OUT_D) {
        const int id = tid >> 2;
        double psi = ((double)phi[tid]
                    - (double)id * (double)f * (double)tau[sb]) * INV_2PI_D;
        psi -= floor(psi);                       // [0,1) revs
        const float pr = (float)psi;
        sp = __builtin_amdgcn_sinf(pr);
        cp = __builtin_amdgcn_sinf(__builtin_amdgcn_fractf(pr + 0.25f));
        ad = a[tid];
    }

    // ---- rotation setup: phase(t=c+32k) = step_rev*c + k*(32*step_rev) revs ----
    const float step_rev = (float)i * f * (T_WAV * INV_2PI_F);   // <= ~0.26 rev
    const float r0   = __builtin_amdgcn_fractf(step_rev * (float)c);          // init angle
    const float rd   = __builtin_amdgcn_fractf(step_rev * 32.0f);             // delta angle
    float sv = __builtin_amdgcn_sinf(r0);
    float cv = __builtin_amdgcn_sinf(__builtin_amdgcn_fractf(r0 + 0.25f));
    const float S = __builtin_amdgcn_sinf(rd);
    const float C = __builtin_amdgcn_sinf(__builtin_amdgcn_fractf(rd + 0.25f));

    __syncthreads();

    float P = 0.0f, Q = 0.0f;
    #pragma unroll 4
    for (int k = 0; k < TIME_LEN / 32; ++k) {    // 20 iters, t = c + 32k
        const float xv = xs[c + (k << 5)];       // 32 consecutive addrs, 2-way dup = free
        P = fmaf(xv, sv, P);
        Q = fmaf(xv, cv, Q);
        const float ns = fmaf(sv, C, cv * S);    // rotate by delta
        const float nc = fmaf(cv, C, -sv * S);
        sv = ns; cv = nc;
    }
    // reduce 32 c-partials (within half-wave: lane xor on bits 0..4)
    #pragma unroll
    for (int off = 1; off < 32; off <<= 1) {
        P += __shfl_xor(P, off);
        Q += __shfl_xor(Q, off);
    }
    if (c == 0) { PQ[0][i] = P; PQ[1][i] = Q; }
    __syncthreads();

    // ---- combine + store ----
    if (tid < OUT_D) {
        const int id = tid >> 2;
        out[(size_t)sb * OUT_D + tid] = ad * fmaf(cp, PQ[0][id], sp * PQ[1][id]);
    }
}

extern "C" void kernel_launch(void* const* d_in, const int* in_sizes, int n_in,
                              void* d_out, int out_size, void* d_ws, size_t ws_size,
                              hipStream_t stream) {
    const float* x   = (const float*)d_in[0];
    const float* nlf = (const float*)d_in[1];
    const float* tau = (const float*)d_in[2];
    const float* a   = (const float*)d_in[3];
    const float* phi = (const float*)d_in[4];
    float* out = (float*)d_out;

    sinenet_kernel<<<dim3(NUM_SB), dim3(1024), 0, stream>>>(x, nlf, tau, a, phi, out);
}